// Round 3
// baseline (134.341 us; speedup 1.0000x reference)
//
#include <hip/hip_runtime.h>

// FixedLearnableTensorSketch: B=4096, L=4096, A=4, D=128.
//
// R7: re-fuse hist+MLP with the overlap structure R4 lacked.
//  - RPB=2, grid=2048, __launch_bounds__(256,4) -> 4 blocks/CU resident,
//    2 batches per CU: batch 2's sequence stream overlaps batch 1's MLP
//    tail (R6's split left HBM idle during the 4-5 us mlp dispatch and
//    paid a dispatch gap + counts round-trip through global).
//  - Histogram accumulates in u32 8-bit fields (16 increments/row/thread,
//    max 16 <= 255): add32 not add64, ~2 fewer VALU ops per int; widened
//    to u64 16-bit fields once before the 64-lane shuffle reduce.
//  - MLP keeps R6's winning mapping: 8-way k-split x 4 cols/thread,
//    W elements read exactly once per block (L2-resident, 128 KiB).
//    psum[8][2][128] = 8 KiB; total LDS ~10.3 KiB.
//
// Counter model (R5/R6): dur_us carries ~100 us of harness poison-fill
// time (268 MB fillBufferAligned at 82% HBM peak, top-5 every round);
// kernel-attributable time is ~16-18 us in R6. This targets ~13-14 us.

static constexpr int Lc = 4096;
static constexpr int Ac = 4;
static constexpr int Dc = 128;
static constexpr int RPB = 2;    // rows per block

static __device__ __forceinline__ unsigned long long expand8to16(unsigned c) {
    // u32 with 4x8-bit fields -> u64 with 4x16-bit fields
    return  (unsigned long long)(c         & 0xFFu)
         | ((unsigned long long)((c >>  8) & 0xFFu) << 16)
         | ((unsigned long long)((c >> 16) & 0xFFu) << 32)
         | ((unsigned long long)( c >> 24        ) << 48);
}

__global__ __launch_bounds__(256, 4)
void fused_sketch_kernel(
    const int*   __restrict__ seq,        // [B, L]
    const float* __restrict__ baseline,   // [B, D]
    const float* __restrict__ char_scales,// [A]
    const float* __restrict__ dim_w,      // [D]
    const float* __restrict__ sk_bias,    // [D]
    const float* __restrict__ mods,       // [A, D]
    const float* __restrict__ W1,         // [D, D]
    const float* __restrict__ b1,         // [D]
    const float* __restrict__ W2,         // [D, D]
    const float* __restrict__ b2,         // [D]
    float*       __restrict__ out)        // [B, D]
{
    __shared__ unsigned long long part[RPB][4];
    __shared__ float counts_lds[RPB][Ac];
    __shared__ __align__(16) float e_lds[RPB][Dc];
    __shared__ __align__(16) float h_lds[RPB][Dc];
    __shared__ __align__(16) float psum[8][RPB][Dc];   // 8 KiB

    const int t    = threadIdx.x;
    const int wave = t >> 6;
    const int lane = t & 63;
    const long long r0 = (long long)blockIdx.x * RPB;

    // ---- Phase 1: histogram, both rows per thread, u32 8-bit fields ----
    {
        const int4* p0 = reinterpret_cast<const int4*>(seq + r0 * Lc);
        const int4* p1 = reinterpret_cast<const int4*>(seq + (r0 + 1) * Lc);
        unsigned c0 = 0u, c1 = 0u;
        #pragma unroll
        for (int i = 0; i < Lc / 4 / 256; ++i) {      // 4 iters, int4 each row
            const int4 a = p0[i * 256 + t];
            const int4 b = p1[i * 256 + t];
            c0 += 1u << (((unsigned)a.x & 3u) << 3);
            c0 += 1u << (((unsigned)a.y & 3u) << 3);
            c0 += 1u << (((unsigned)a.z & 3u) << 3);
            c0 += 1u << (((unsigned)a.w & 3u) << 3);
            c1 += 1u << (((unsigned)b.x & 3u) << 3);
            c1 += 1u << (((unsigned)b.y & 3u) << 3);
            c1 += 1u << (((unsigned)b.z & 3u) << 3);
            c1 += 1u << (((unsigned)b.w & 3u) << 3);
        }
        unsigned long long w0 = expand8to16(c0);
        unsigned long long w1 = expand8to16(c1);
        #pragma unroll
        for (int off = 32; off > 0; off >>= 1) {
            w0 += __shfl_down(w0, off);
            w1 += __shfl_down(w1, off);
        }
        if (lane == 0) { part[0][wave] = w0; part[1][wave] = w1; }
    }
    __syncthreads();
    if (t < RPB * 4) {
        const int rw = t >> 2, a = t & 3;
        const unsigned long long s =
            part[rw][0] + part[rw][1] + part[rw][2] + part[rw][3];
        counts_lds[rw][a] = (float)((unsigned)((s >> (a * 16)) & 0xFFFFull));
    }
    __syncthreads();

    const int j    = t & (Dc - 1);   // 0..127
    const int half = t >> 7;         // 0 or 1 == row index (RPB=2)
    const float invL = 1.0f / (float)Lc;

    // ---- Phase 2: e = (baseline*dw + bias)*scale + mods -> LDS ----
    {
        const float s0 = char_scales[0], s1 = char_scales[1],
                    s2 = char_scales[2], s3 = char_scales[3];
        const float dwj = dim_w[j], bj = sk_bias[j];
        const float m0 = mods[0 * Dc + j], m1 = mods[1 * Dc + j],
                    m2 = mods[2 * Dc + j], m3 = mods[3 * Dc + j];
        const int r = half;
        const float c0 = counts_lds[r][0], c1 = counts_lds[r][1],
                    c2 = counts_lds[r][2], c3 = counts_lds[r][3];
        const float scale = (c0 * s0 + c1 * s1 + c2 * s2 + c3 * s3) * invL;
        const float md    = (c0 * m0 + c1 * m1 + c2 * m2 + c3 * m3) * invL;
        const float base  = baseline[(r0 + r) * Dc + j];
        e_lds[r][j] = (base * dwj + bj) * scale + md;
    }
    __syncthreads();

    // GEMM mapping: q = t>>5 (k-sixteenth block, k in [q*16, q*16+16)),
    // jg = t&31 owns output columns {jg, jg+32, jg+64, jg+96}.
    const int q  = t >> 5;           // 0..7
    const int jg = t & 31;
    const int k0 = q * 16;

    // ---- Phase 3: h = relu(e @ W1^T + b1) ----
    {
        float a0[RPB], a1[RPB], a2[RPB], a3[RPB];
        #pragma unroll
        for (int r = 0; r < RPB; ++r) { a0[r] = 0.f; a1[r] = 0.f; a2[r] = 0.f; a3[r] = 0.f; }
        const float4* w0 = reinterpret_cast<const float4*>(W1 + (jg     ) * Dc + k0);
        const float4* w1 = reinterpret_cast<const float4*>(W1 + (jg + 32) * Dc + k0);
        const float4* w2 = reinterpret_cast<const float4*>(W1 + (jg + 64) * Dc + k0);
        const float4* w3 = reinterpret_cast<const float4*>(W1 + (jg + 96) * Dc + k0);
        #pragma unroll
        for (int kk = 0; kk < 4; ++kk) {
            const float4 wa = w0[kk];
            const float4 wb = w1[kk];
            const float4 wc = w2[kk];
            const float4 wd = w3[kk];
            #pragma unroll
            for (int r = 0; r < RPB; ++r) {
                const float4 e = *reinterpret_cast<const float4*>(&e_lds[r][k0 + kk * 4]);
                a0[r] += wa.x * e.x + wa.y * e.y + wa.z * e.z + wa.w * e.w;
                a1[r] += wb.x * e.x + wb.y * e.y + wb.z * e.z + wb.w * e.w;
                a2[r] += wc.x * e.x + wc.y * e.y + wc.z * e.z + wc.w * e.w;
                a3[r] += wd.x * e.x + wd.y * e.y + wd.z * e.z + wd.w * e.w;
            }
        }
        #pragma unroll
        for (int r = 0; r < RPB; ++r) {
            psum[q][r][jg     ] = a0[r];
            psum[q][r][jg + 32] = a1[r];
            psum[q][r][jg + 64] = a2[r];
            psum[q][r][jg + 96] = a3[r];
        }
    }
    __syncthreads();
    {
        const int r = half;
        float s = b1[j];
        #pragma unroll
        for (int qq = 0; qq < 8; ++qq) s += psum[qq][r][j];
        h_lds[r][j] = s > 0.0f ? s : 0.0f;
    }
    __syncthreads();

    // ---- Phase 4: out = h @ W2^T + b2 (same mapping) ----
    {
        float a0[RPB], a1[RPB], a2[RPB], a3[RPB];
        #pragma unroll
        for (int r = 0; r < RPB; ++r) { a0[r] = 0.f; a1[r] = 0.f; a2[r] = 0.f; a3[r] = 0.f; }
        const float4* w0 = reinterpret_cast<const float4*>(W2 + (jg     ) * Dc + k0);
        const float4* w1 = reinterpret_cast<const float4*>(W2 + (jg + 32) * Dc + k0);
        const float4* w2 = reinterpret_cast<const float4*>(W2 + (jg + 64) * Dc + k0);
        const float4* w3 = reinterpret_cast<const float4*>(W2 + (jg + 96) * Dc + k0);
        #pragma unroll
        for (int kk = 0; kk < 4; ++kk) {
            const float4 wa = w0[kk];
            const float4 wb = w1[kk];
            const float4 wc = w2[kk];
            const float4 wd = w3[kk];
            #pragma unroll
            for (int r = 0; r < RPB; ++r) {
                const float4 h = *reinterpret_cast<const float4*>(&h_lds[r][k0 + kk * 4]);
                a0[r] += wa.x * h.x + wa.y * h.y + wa.z * h.z + wa.w * h.w;
                a1[r] += wb.x * h.x + wb.y * h.y + wb.z * h.z + wb.w * h.w;
                a2[r] += wc.x * h.x + wc.y * h.y + wc.z * h.z + wc.w * h.w;
                a3[r] += wd.x * h.x + wd.y * h.y + wd.z * h.z + wd.w * h.w;
            }
        }
        #pragma unroll
        for (int r = 0; r < RPB; ++r) {
            psum[q][r][jg     ] = a0[r];
            psum[q][r][jg + 32] = a1[r];
            psum[q][r][jg + 64] = a2[r];
            psum[q][r][jg + 96] = a3[r];
        }
    }
    __syncthreads();
    {
        const int r = half;
        float s = b2[j];
        #pragma unroll
        for (int qq = 0; qq < 8; ++qq) s += psum[qq][r][j];
        out[(r0 + r) * Dc + j] = s;
    }
}

extern "C" void kernel_launch(void* const* d_in, const int* in_sizes, int n_in,
                              void* d_out, int out_size, void* d_ws, size_t ws_size,
                              hipStream_t stream) {
    const int*   seq         = (const int*)  d_in[0];
    const float* baseline    = (const float*)d_in[1];
    const float* char_scales = (const float*)d_in[2];
    const float* dim_w       = (const float*)d_in[3];
    const float* sk_bias     = (const float*)d_in[4];
    const float* mods        = (const float*)d_in[5];
    const float* W1          = (const float*)d_in[6];
    const float* b1          = (const float*)d_in[7];
    const float* W2          = (const float*)d_in[8];
    const float* b2          = (const float*)d_in[9];
    float*       out         = (float*)d_out;

    const int B = in_sizes[1] / Dc;          // 4096
    hipLaunchKernelGGL(fused_sketch_kernel, dim3(B / RPB), dim3(256), 0, stream,
                       seq, baseline, char_scales, dim_w, sk_bias, mods,
                       W1, b1, W2, b2, out);
}

// Round 4
// 117.413 us; speedup vs baseline: 1.1442x; 1.1442x over previous
//
#include <hip/hip_runtime.h>

// FixedLearnableTensorSketch: B=4096, L=4096, A=4, D=128.
//
// R8: revert to the R6 split (best measured: 117.0 us) after R7's fusion
// regressed to 134.3 (counters showed the fused kernel latency/convoy-
// bound: 46-52 us, VALUBusy 13%, 1.4 TB/s effective stream — resident
// blocks phase-lock, HBM idles during MLP phases). Split gives each
// phase the whole machine.
//
// R8 deltas vs R6:
//  - hist: __launch_bounds__(256,8) (all 2048 blocks resident, 2x
//    in-flight stream bytes/CU) + u32 8-bit-field counters (R7's cheaper
//    inner loop; widened to u64 16-bit fields before the wave reduce).
//  - mlp: consecutive-column mapping (thread owns cols 4jg..4jg+3):
//    psum writes are single b128 stores (4x fewer LDS write instrs,
//    conflict-free full-bank coverage); W1+W2 fully preloaded into
//    registers at kernel start so scattered L2 W-reads overlap the
//    counts/baseline loads and e-staging instead of stalling phases 3/4.
//    Per-output FMA order unchanged -> absmax bit-identical.

static constexpr int Lc = 4096;
static constexpr int Ac = 4;
static constexpr int Dc = 128;

static __device__ __forceinline__ unsigned long long expand8to16(unsigned c) {
    // u32 with 4x8-bit fields -> u64 with 4x16-bit fields
    return  (unsigned long long)(c         & 0xFFu)
         | ((unsigned long long)((c >>  8) & 0xFFu) << 16)
         | ((unsigned long long)((c >> 16) & 0xFFu) << 32)
         | ((unsigned long long)( c >> 24        ) << 48);
}

// ---------------- Kernel 1: per-row histogram ----------------
// 2 rows per block, 256 threads. Per-thread 8-bit fields (max 16/field),
// widened to 16-bit fields for the cross-lane reduce (row max 4096 < 2^16).
static constexpr int HROWS = 2;

__global__ __launch_bounds__(256, 8)
void hist_kernel(const int* __restrict__ seq, float* __restrict__ counts_out)
{
    const int t    = threadIdx.x;
    const int wave = t >> 6;
    const int lane = t & 63;
    const long long r0 = (long long)blockIdx.x * HROWS;

    __shared__ unsigned long long part[HROWS][4];

    unsigned c0 = 0u, c1 = 0u;
    {
        const int4* p0 = reinterpret_cast<const int4*>(seq + r0 * Lc);
        const int4* p1 = reinterpret_cast<const int4*>(seq + (r0 + 1) * Lc);
        #pragma unroll
        for (int i = 0; i < Lc / 4 / 256; ++i) {      // 4 iters, int4 each row
            const int4 a = p0[i * 256 + t];
            const int4 b = p1[i * 256 + t];
            c0 += 1u << (((unsigned)a.x & 3u) << 3);
            c0 += 1u << (((unsigned)a.y & 3u) << 3);
            c0 += 1u << (((unsigned)a.z & 3u) << 3);
            c0 += 1u << (((unsigned)a.w & 3u) << 3);
            c1 += 1u << (((unsigned)b.x & 3u) << 3);
            c1 += 1u << (((unsigned)b.y & 3u) << 3);
            c1 += 1u << (((unsigned)b.z & 3u) << 3);
            c1 += 1u << (((unsigned)b.w & 3u) << 3);
        }
    }
    unsigned long long w0 = expand8to16(c0);
    unsigned long long w1 = expand8to16(c1);
    #pragma unroll
    for (int off = 32; off > 0; off >>= 1) {
        w0 += __shfl_down(w0, off);
        w1 += __shfl_down(w1, off);
    }
    if (lane == 0) { part[0][wave] = w0; part[1][wave] = w1; }
    __syncthreads();

    if (t < HROWS * 4) {
        const int rw = t >> 2, a = t & 3;
        const unsigned long long s =
            part[rw][0] + part[rw][1] + part[rw][2] + part[rw][3];
        // counts for row r live at out[r*Dc + a], a = 0..3 (scratch)
        counts_out[(r0 + rw) * Dc + a] =
            (float)((unsigned)((s >> (a * 16)) & 0xFFFFull));
    }
}

// ---------------- Kernel 2: affine + 2-layer MLP ----------------
static constexpr int RPB = 8;   // rows per block

__global__ __launch_bounds__(256, 2)
void mlp_kernel(
    const float* __restrict__ baseline,   // [B, D]
    const float* __restrict__ char_scales,// [A]
    const float* __restrict__ dim_w,      // [D]
    const float* __restrict__ sk_bias,    // [D]
    const float* __restrict__ mods,       // [A, D]
    const float* __restrict__ W1,         // [D, D]
    const float* __restrict__ b1,         // [D]
    const float* __restrict__ W2,         // [D, D]
    const float* __restrict__ b2,         // [D]
    float*       __restrict__ out)        // [B, D]; cols 0..3 hold counts on entry
{
    __shared__ __align__(16) float e_lds[RPB][Dc];
    __shared__ __align__(16) float h_lds[RPB][Dc];
    __shared__ __align__(16) float psum[8][RPB][Dc];   // 32 KiB

    const int t    = threadIdx.x;
    const int r0   = blockIdx.x * RPB;
    const int j    = t & (Dc - 1);   // 0..127
    const int half = t >> 7;         // 0 or 1
    const float invL = 1.0f / (float)Lc;

    // GEMM thread mapping: q = t>>5 (k-eighth, k in [q*16, q*16+16)),
    // jg = t&31 owns CONSECUTIVE output columns 4*jg .. 4*jg+3.
    const int q  = t >> 5;           // 0..7
    const int jg = t & 31;
    const int k0 = q * 16;
    const int c0col = 4 * jg;

    // ---- Preload W1 + W2 fragments into registers (hides L2 latency
    // under phase 2's global reads + LDS staging). 32 float4 = 128 VGPR.
    float4 w1r[4][4], w2r[4][4];
    #pragma unroll
    for (int c = 0; c < 4; ++c) {
        const float4* p1 = reinterpret_cast<const float4*>(W1 + (c0col + c) * Dc + k0);
        const float4* p2 = reinterpret_cast<const float4*>(W2 + (c0col + c) * Dc + k0);
        #pragma unroll
        for (int kk = 0; kk < 4; ++kk) { w1r[c][kk] = p1[kk]; w2r[c][kk] = p2[kk]; }
    }

    // ---- Phase 2: e = (baseline*dw + bias)*scale + mods -> LDS ----
    {
        const float s0 = char_scales[0], s1 = char_scales[1],
                    s2 = char_scales[2], s3 = char_scales[3];
        const float dwj = dim_w[j], bj = sk_bias[j];
        const float m0 = mods[0 * Dc + j], m1 = mods[1 * Dc + j],
                    m2 = mods[2 * Dc + j], m3 = mods[3 * Dc + j];
        #pragma unroll
        for (int rr = 0; rr < RPB / 2; ++rr) {
            const int r = half + rr * 2;
            const float* cp = out + (long long)(r0 + r) * Dc;  // counts scratch
            const float cc0 = cp[0], cc1 = cp[1], cc2 = cp[2], cc3 = cp[3];
            const float scale = (cc0 * s0 + cc1 * s1 + cc2 * s2 + cc3 * s3) * invL;
            const float md    = (cc0 * m0 + cc1 * m1 + cc2 * m2 + cc3 * m3) * invL;
            const float base  = baseline[(long long)(r0 + r) * Dc + j];
            e_lds[r][j] = (base * dwj + bj) * scale + md;
        }
    }
    __syncthreads();

    // ---- Phase 3: h = relu(e @ W1^T + b1) ----
    {
        float a0[RPB], a1[RPB], a2[RPB], a3[RPB];
        #pragma unroll
        for (int r = 0; r < RPB; ++r) { a0[r] = 0.f; a1[r] = 0.f; a2[r] = 0.f; a3[r] = 0.f; }
        #pragma unroll
        for (int kk = 0; kk < 4; ++kk) {
            const float4 wa = w1r[0][kk];
            const float4 wb = w1r[1][kk];
            const float4 wc = w1r[2][kk];
            const float4 wd = w1r[3][kk];
            #pragma unroll
            for (int r = 0; r < RPB; ++r) {
                const float4 e = *reinterpret_cast<const float4*>(&e_lds[r][k0 + kk * 4]);
                a0[r] += wa.x * e.x + wa.y * e.y + wa.z * e.z + wa.w * e.w;
                a1[r] += wb.x * e.x + wb.y * e.y + wb.z * e.z + wb.w * e.w;
                a2[r] += wc.x * e.x + wc.y * e.y + wc.z * e.z + wc.w * e.w;
                a3[r] += wd.x * e.x + wd.y * e.y + wd.z * e.z + wd.w * e.w;
            }
        }
        #pragma unroll
        for (int r = 0; r < RPB; ++r) {
            *reinterpret_cast<float4*>(&psum[q][r][c0col]) =
                make_float4(a0[r], a1[r], a2[r], a3[r]);
        }
    }
    __syncthreads();
    {
        const float b = b1[j];
        #pragma unroll
        for (int rr = 0; rr < RPB / 2; ++rr) {
            const int r = half + rr * 2;
            float s = b;
            #pragma unroll
            for (int qq = 0; qq < 8; ++qq) s += psum[qq][r][j];
            h_lds[r][j] = s > 0.0f ? s : 0.0f;
        }
    }
    __syncthreads();

    // ---- Phase 4: out = h @ W2^T + b2 (same mapping) ----
    {
        float a0[RPB], a1[RPB], a2[RPB], a3[RPB];
        #pragma unroll
        for (int r = 0; r < RPB; ++r) { a0[r] = 0.f; a1[r] = 0.f; a2[r] = 0.f; a3[r] = 0.f; }
        #pragma unroll
        for (int kk = 0; kk < 4; ++kk) {
            const float4 wa = w2r[0][kk];
            const float4 wb = w2r[1][kk];
            const float4 wc = w2r[2][kk];
            const float4 wd = w2r[3][kk];
            #pragma unroll
            for (int r = 0; r < RPB; ++r) {
                const float4 h = *reinterpret_cast<const float4*>(&h_lds[r][k0 + kk * 4]);
                a0[r] += wa.x * h.x + wa.y * h.y + wa.z * h.z + wa.w * h.w;
                a1[r] += wb.x * h.x + wb.y * h.y + wb.z * h.z + wb.w * h.w;
                a2[r] += wc.x * h.x + wc.y * h.y + wc.z * h.z + wc.w * h.w;
                a3[r] += wd.x * h.x + wd.y * h.y + wd.z * h.z + wd.w * h.w;
            }
        }
        #pragma unroll
        for (int r = 0; r < RPB; ++r) {
            *reinterpret_cast<float4*>(&psum[q][r][c0col]) =
                make_float4(a0[r], a1[r], a2[r], a3[r]);
        }
    }
    __syncthreads();
    {
        const float b = b2[j];
        #pragma unroll
        for (int rr = 0; rr < RPB / 2; ++rr) {
            const int r = half + rr * 2;
            float s = b;
            #pragma unroll
            for (int qq = 0; qq < 8; ++qq) s += psum[qq][r][j];
            out[(long long)(r0 + r) * Dc + j] = s;
        }
    }
}

extern "C" void kernel_launch(void* const* d_in, const int* in_sizes, int n_in,
                              void* d_out, int out_size, void* d_ws, size_t ws_size,
                              hipStream_t stream) {
    const int*   seq         = (const int*)  d_in[0];
    const float* baseline    = (const float*)d_in[1];
    const float* char_scales = (const float*)d_in[2];
    const float* dim_w       = (const float*)d_in[3];
    const float* sk_bias     = (const float*)d_in[4];
    const float* mods        = (const float*)d_in[5];
    const float* W1          = (const float*)d_in[6];
    const float* b1          = (const float*)d_in[7];
    const float* W2          = (const float*)d_in[8];
    const float* b2          = (const float*)d_in[9];
    float*       out         = (float*)d_out;

    const int B = in_sizes[1] / Dc;          // 4096

    // Dispatch 1: histogram -> counts stashed in out[:, 0:4]
    hipLaunchKernelGGL(hist_kernel, dim3(B / HROWS), dim3(256), 0, stream,
                       seq, out);
    // Dispatch 2: affine + MLP (stream-ordered after hist)
    hipLaunchKernelGGL(mlp_kernel, dim3(B / RPB), dim3(256), 0, stream,
                       baseline, char_scales, dim_w, sk_bias, mods,
                       W1, b1, W2, b2, out);
}